// Round 1
// baseline (1001.333 us; speedup 1.0000x reference)
//
#include <hip/hip_runtime.h>

#define TT    32        // timesteps
#define KDIM  262144    // fan-in (C*RF*L)
#define NFEAT 512       // output features
#define NF_BLOCK 16     // features per block (4 waves x 4 feats)
#define FPT   4         // features per thread
#define BK    256       // k elements staged in LDS per step

// ---------------------------------------------------------------------------
// Kernel 1: partial GEMM. grid = (32 f-tiles, nkc k-chunks), block = 256.
// Lanes run along k; each thread owns 4 features x 32 timesteps.
// ---------------------------------------------------------------------------
__global__ __launch_bounds__(256, 2)
void gemm_partial(const float* __restrict__ x, const float* __restrict__ w,
                  float* __restrict__ partial, int KC) {
    __shared__ float xs[TT][BK];      // 32 KB

    const int tid  = threadIdx.x;
    const int wave = tid >> 6;
    const int lane = tid & 63;
    const int ftile  = blockIdx.x;    // 0..31
    const int kchunk = blockIdx.y;    // 0..nkc-1
    const int f0 = ftile * NF_BLOCK + wave * FPT;
    const size_t kbase = (size_t)kchunk * (size_t)KC;

    float acc[FPT][TT];
#pragma unroll
    for (int j = 0; j < FPT; ++j)
#pragma unroll
        for (int t = 0; t < TT; ++t) acc[j][t] = 0.f;

    const float* wp[FPT];
#pragma unroll
    for (int j = 0; j < FPT; ++j)
        wp[j] = w + (size_t)(f0 + j) * KDIM + kbase + (size_t)(lane << 2);

    // prefetch weight for first step
    float4 wv[FPT];
#pragma unroll
    for (int j = 0; j < FPT; ++j) wv[j] = *(const float4*)(wp[j]);

    for (int ks = 0; ks < KC; ks += BK) {
        // ---- stage x tile into LDS (each wave handles rows wave, wave+4, ...)
        float4 xr[8];
#pragma unroll
        for (int r = 0; r < 8; ++r) {
            const int t = r * 4 + wave;
            xr[r] = *(const float4*)(x + (size_t)t * KDIM + kbase + ks + (lane << 2));
        }
        __syncthreads();              // previous step's readers done
#pragma unroll
        for (int r = 0; r < 8; ++r)
            *(float4*)(&xs[r * 4 + wave][lane << 2]) = xr[r];
        __syncthreads();              // tile ready

        // ---- prefetch next step's weights (overlaps with compute below)
        const bool more = (ks + BK) < KC;
        float4 wn[FPT];
        if (more) {
#pragma unroll
            for (int j = 0; j < FPT; ++j)
                wn[j] = *(const float4*)(wp[j] + ks + BK);
        }

        // ---- compute: 32 ds_read_b128 + 512 v_fmac per thread
#pragma unroll
        for (int t = 0; t < TT; ++t) {
            const float4 xv = *(const float4*)(&xs[t][lane << 2]);
#pragma unroll
            for (int j = 0; j < FPT; ++j) {
                acc[j][t] += wv[j].x * xv.x;
                acc[j][t] += wv[j].y * xv.y;
                acc[j][t] += wv[j].z * xv.z;
                acc[j][t] += wv[j].w * xv.w;
            }
        }

        if (more) {
#pragma unroll
            for (int j = 0; j < FPT; ++j) wv[j] = wn[j];
        }
    }

    // ---- butterfly reduce across the 64 lanes of the wave
#pragma unroll
    for (int j = 0; j < FPT; ++j) {
#pragma unroll
        for (int t = 0; t < TT; ++t) {
            float v = acc[j][t];
            v += __shfl_xor(v, 32, 64);
            v += __shfl_xor(v, 16, 64);
            v += __shfl_xor(v,  8, 64);
            v += __shfl_xor(v,  4, 64);
            v += __shfl_xor(v,  2, 64);
            v += __shfl_xor(v,  1, 64);
            acc[j][t] = v;
        }
    }

    if (lane == 0) {
#pragma unroll
        for (int j = 0; j < FPT; ++j) {
            float* p = partial + ((size_t)kchunk * NFEAT + (f0 + j)) * TT;
#pragma unroll
            for (int t = 0; t < TT; t += 4)
                *(float4*)(p + t) = make_float4(acc[j][t], acc[j][t+1],
                                                acc[j][t+2], acc[j][t+3]);
        }
    }
}

// ---------------------------------------------------------------------------
// Kernel 2a: deterministic reduction over k-chunks -> raw potentials [o][t]
// ---------------------------------------------------------------------------
__global__ __launch_bounds__(256)
void reduce_chunks(const float* __restrict__ partial, int nkc,
                   float* __restrict__ potraw) {
    const int id = blockIdx.x * 256 + threadIdx.x;   // 0..16383 = o*32+t
    float s = 0.f;
    for (int c = 0; c < nkc; ++c)
        s += partial[(size_t)c * (NFEAT * TT) + id];
    potraw[id] = s;
}

// ---------------------------------------------------------------------------
// Kernel 2b: threshold + spike logic + 8-winner k-WTA + binary output.
// Single block, 512 threads (one per feature). Exact fp32 replication of the
// reference epilogue, numpy-argmax first-index tie-break included.
// ---------------------------------------------------------------------------
__global__ __launch_bounds__(512)
void finalize(const float* __restrict__ potraw, float* __restrict__ out) {
    const int o = threadIdx.x;       // feature index

    float pot[TT];
#pragma unroll
    for (int t = 0; t < TT; ++t) {
        const float s = potraw[o * TT + t];
        pot[t] = (s < 0.2f) ? 0.f : s;     // zero strictly below threshold
    }

    int cnt = 0;
#pragma unroll
    for (int t = 0; t < TT; ++t) cnt += (pot[t] > 0.f) ? 1 : 0;

    int first = TT - cnt;                  // clip((T - count), 0, T-1)
    if (first > TT - 1) first = TT - 1;
    float value = 0.f;
#pragma unroll
    for (int t = 0; t < TT; ++t)
        if (t == first) value = pot[t];

    __shared__ float rv[NFEAT];
    __shared__ int   ri[NFEAT];
    __shared__ float tot[NFEAT];
    __shared__ int   sel[NFEAT];

    // ---- v = max(spikes * values) * T   (block max of value; value=0 if cnt=0)
    rv[o] = (cnt > 0) ? value : 0.f;
    __syncthreads();
    for (int s = 256; s > 0; s >>= 1) {
        if (o < s) rv[o] = fmaxf(rv[o], rv[o + s]);
        __syncthreads();
    }
    const float v = rv[0] * (float)TT;
    __syncthreads();

    // total[o] = count * value + count * v   (0 when no spikes)
    tot[o] = (float)cnt * (value + v);
    sel[o] = 0;
    __syncthreads();

    // ---- iterative k-WTA, 8 winners, first-index argmax ties
    for (int it = 0; it < 8; ++it) {
        rv[o] = tot[o]; ri[o] = o;
        __syncthreads();
        for (int s = 256; s > 0; s >>= 1) {
            if (o < s) {
                const float v2 = rv[o + s];
                const int   i2 = ri[o + s];
                if (v2 > rv[o] || (v2 == rv[o] && i2 < ri[o])) {
                    rv[o] = v2; ri[o] = i2;
                }
            }
            __syncthreads();
        }
        if (o == 0) {
            if (rv[0] != 0.f) sel[ri[0]] = 1;
            tot[ri[0]] = 0.f;
        }
        __syncthreads();
    }

    // ---- out[t, o] = sign(pot * coef)  -> binary spikes of selected features
#pragma unroll
    for (int t = 0; t < TT; ++t)
        out[t * NFEAT + o] = (sel[o] && pot[t] > 0.f) ? 1.f : 0.f;
}

// ---------------------------------------------------------------------------
extern "C" void kernel_launch(void* const* d_in, const int* in_sizes, int n_in,
                              void* d_out, int out_size, void* d_ws, size_t ws_size,
                              hipStream_t stream) {
    const float* x = (const float*)d_in[0];   // rec_field (32,1,64,4096)
    const float* w = (const float*)d_in[1];   // weight   (512,1,64,4096)
    float* out = (float*)d_out;               // (32,512,1,1) flat

    // partials [nkc][512][32] + potraw [512][32] in workspace
    int nkc = 32;
    while (nkc > 1 &&
           ((size_t)nkc * NFEAT * TT * sizeof(float) + NFEAT * TT * sizeof(float)) > ws_size)
        nkc >>= 1;
    const int KC = KDIM / nkc;

    float* partial = (float*)d_ws;
    float* potraw  = partial + (size_t)nkc * NFEAT * TT;

    gemm_partial<<<dim3(32, nkc), 256, 0, stream>>>(x, w, partial, KC);
    reduce_chunks<<<(NFEAT * TT) / 256, 256, 0, stream>>>(partial, nkc, potraw);
    finalize<<<1, NFEAT, 0, stream>>>(potraw, out);
}

// Round 2
// 889.124 us; speedup vs baseline: 1.1262x; 1.1262x over previous
//
#include <hip/hip_runtime.h>

#define TT    32        // timesteps
#define KDIM  262144    // fan-in (C*RF*L)
#define NFEAT 512       // output features
#define NFB   16        // features per block
#define FPT   8         // features per thread
#define TPT   8         // timesteps per thread
#define BK    256       // k elements staged per step

// async global->LDS, 16B per lane; LDS dest = wave-uniform row base + lane*16
__device__ __forceinline__ void async_ld16(const float* g, float* lds_row) {
    __builtin_amdgcn_global_load_lds(
        (const __attribute__((address_space(1))) unsigned int*)g,
        (__attribute__((address_space(3))) unsigned int*)lds_row, 16, 0, 0);
}

// ---------------------------------------------------------------------------
// Kernel 1: partial GEMM. grid = (32 f-tiles, nkc k-chunks), block = 512.
// 8 waves = 2 fgrps x 4 tgrps. Lanes run along k (lane*4 within BK=256).
// Weights stream global->VGPR (each b128 feeds 8t x 4k = 32 FMAs here, 4
// t-group duplicates dedup in L2). x double-buffered in LDS via
// global_load_lds. acc[8][8] = 64 VGPRs -> no spill.
// ---------------------------------------------------------------------------
__global__ __launch_bounds__(512, 2)
void gemm_partial(const float* __restrict__ x, const float* __restrict__ w,
                  float* __restrict__ partial, int KC) {
    __shared__ float xs[2][TT][BK];      // 2 x 32 KB

    const int tid  = threadIdx.x;
    const int lane = tid & 63;
    const int wave = tid >> 6;           // 0..7
    const int fgrp = wave & 1;           // 0..1
    const int tgrp = wave >> 1;          // 0..3
    const int ftile  = blockIdx.x;       // 0..31
    const int kchunk = blockIdx.y;       // 0..nkc-1
    const int f0 = ftile * NFB + fgrp * FPT;
    const int t0 = tgrp * TPT;
    const size_t kbase = (size_t)kchunk * (size_t)KC;

    float acc[FPT][TPT];
#pragma unroll
    for (int j = 0; j < FPT; ++j)
#pragma unroll
        for (int t = 0; t < TPT; ++t) acc[j][t] = 0.f;

    const float* wbase = w + (size_t)f0 * KDIM + kbase + (lane << 2);
    const float* xbase = x + kbase + (lane << 2);

    // prologue: stage buffer 0 (rows wave*4 .. wave*4+3)
#pragma unroll
    for (int r = 0; r < 4; ++r) {
        const int t = wave * 4 + r;
        async_ld16(xbase + (size_t)t * KDIM, &xs[0][t][0]);
    }

    int cur = 0;
    for (int ks = 0; ks < KC; ks += BK) {
        __syncthreads();                 // xs[cur] ready (drains stage + loads)

        // stage next buffer (no reader of xs[cur^1] is active past the barrier)
        if (ks + BK < KC) {
#pragma unroll
            for (int r = 0; r < 4; ++r) {
                const int t = wave * 4 + r;
                async_ld16(xbase + (size_t)t * KDIM + (ks + BK), &xs[cur ^ 1][t][0]);
            }
        }

        // weights for this step: 8 features x float4, global->reg
        float4 wv[FPT];
#pragma unroll
        for (int j = 0; j < FPT; ++j)
            wv[j] = *(const float4*)(wbase + (size_t)j * KDIM + ks);

        // compute: 8 ds_read_b128 + 256 v_fmac per thread per step
#pragma unroll
        for (int t = 0; t < TPT; ++t) {
            const float4 xv = *(const float4*)(&xs[cur][t0 + t][lane << 2]);
#pragma unroll
            for (int j = 0; j < FPT; ++j) {
                acc[j][t] = fmaf(wv[j].x, xv.x, acc[j][t]);
                acc[j][t] = fmaf(wv[j].y, xv.y, acc[j][t]);
                acc[j][t] = fmaf(wv[j].z, xv.z, acc[j][t]);
                acc[j][t] = fmaf(wv[j].w, xv.w, acc[j][t]);
            }
        }
        cur ^= 1;
    }

    // butterfly reduce across the 64 k-lanes
#pragma unroll
    for (int j = 0; j < FPT; ++j) {
#pragma unroll
        for (int t = 0; t < TPT; ++t) {
            float v = acc[j][t];
            v += __shfl_xor(v, 32, 64);
            v += __shfl_xor(v, 16, 64);
            v += __shfl_xor(v,  8, 64);
            v += __shfl_xor(v,  4, 64);
            v += __shfl_xor(v,  2, 64);
            v += __shfl_xor(v,  1, 64);
            acc[j][t] = v;
        }
    }

    if (lane == 0) {
#pragma unroll
        for (int j = 0; j < FPT; ++j) {
            float* p = partial + ((size_t)kchunk * NFEAT + (f0 + j)) * TT + t0;
            *(float4*)(p)     = make_float4(acc[j][0], acc[j][1], acc[j][2], acc[j][3]);
            *(float4*)(p + 4) = make_float4(acc[j][4], acc[j][5], acc[j][6], acc[j][7]);
        }
    }
}

// ---------------------------------------------------------------------------
// Kernel 2a: deterministic reduction over k-chunks -> raw potentials [o][t]
// ---------------------------------------------------------------------------
__global__ __launch_bounds__(256)
void reduce_chunks(const float* __restrict__ partial, int nkc,
                   float* __restrict__ potraw) {
    const int id = blockIdx.x * 256 + threadIdx.x;   // 0..16383 = o*32+t
    float s = 0.f;
    for (int c = 0; c < nkc; ++c)
        s += partial[(size_t)c * (NFEAT * TT) + id];
    potraw[id] = s;
}

// ---------------------------------------------------------------------------
// Kernel 2b: threshold + spike logic + 8-winner k-WTA + binary output.
// Single block, 512 threads (one per feature). Exact fp32 replication of the
// reference epilogue, numpy-argmax first-index tie-break included.
// ---------------------------------------------------------------------------
__global__ __launch_bounds__(512)
void finalize(const float* __restrict__ potraw, float* __restrict__ out) {
    const int o = threadIdx.x;       // feature index

    float pot[TT];
#pragma unroll
    for (int t = 0; t < TT; ++t) {
        const float s = potraw[o * TT + t];
        pot[t] = (s < 0.2f) ? 0.f : s;     // zero strictly below threshold
    }

    int cnt = 0;
#pragma unroll
    for (int t = 0; t < TT; ++t) cnt += (pot[t] > 0.f) ? 1 : 0;

    int first = TT - cnt;                  // clip((T - count), 0, T-1)
    if (first > TT - 1) first = TT - 1;
    float value = 0.f;
#pragma unroll
    for (int t = 0; t < TT; ++t)
        if (t == first) value = pot[t];

    __shared__ float rv[NFEAT];
    __shared__ int   ri[NFEAT];
    __shared__ float tot[NFEAT];
    __shared__ int   sel[NFEAT];

    // ---- v = max(spikes * values) * T
    rv[o] = (cnt > 0) ? value : 0.f;
    __syncthreads();
    for (int s = 256; s > 0; s >>= 1) {
        if (o < s) rv[o] = fmaxf(rv[o], rv[o + s]);
        __syncthreads();
    }
    const float v = rv[0] * (float)TT;
    __syncthreads();

    // total[o] = count * value + count * v   (0 when no spikes)
    tot[o] = (float)cnt * (value + v);
    sel[o] = 0;
    __syncthreads();

    // ---- iterative k-WTA, 8 winners, first-index argmax ties
    for (int it = 0; it < 8; ++it) {
        rv[o] = tot[o]; ri[o] = o;
        __syncthreads();
        for (int s = 256; s > 0; s >>= 1) {
            if (o < s) {
                const float v2 = rv[o + s];
                const int   i2 = ri[o + s];
                if (v2 > rv[o] || (v2 == rv[o] && i2 < ri[o])) {
                    rv[o] = v2; ri[o] = i2;
                }
            }
            __syncthreads();
        }
        if (o == 0) {
            if (rv[0] != 0.f) sel[ri[0]] = 1;
            tot[ri[0]] = 0.f;
        }
        __syncthreads();
    }

    // ---- out[t, o] = binary spikes of selected features
#pragma unroll
    for (int t = 0; t < TT; ++t)
        out[t * NFEAT + o] = (sel[o] && pot[t] > 0.f) ? 1.f : 0.f;
}

// ---------------------------------------------------------------------------
extern "C" void kernel_launch(void* const* d_in, const int* in_sizes, int n_in,
                              void* d_out, int out_size, void* d_ws, size_t ws_size,
                              hipStream_t stream) {
    const float* x = (const float*)d_in[0];   // rec_field (32,1,64,4096)
    const float* w = (const float*)d_in[1];   // weight   (512,1,64,4096)
    float* out = (float*)d_out;               // (32,512,1,1) flat

    // partials [nkc][512][32] + potraw [512][32] in workspace
    int nkc = 32;
    while (nkc > 1 &&
           ((size_t)(nkc + 1) * NFEAT * TT * sizeof(float)) > ws_size)
        nkc >>= 1;
    const int KC = KDIM / nkc;

    float* partial = (float*)d_ws;
    float* potraw  = partial + (size_t)nkc * NFEAT * TT;

    gemm_partial<<<dim3(32, nkc), 512, 0, stream>>>(x, w, partial, KC);
    reduce_chunks<<<(NFEAT * TT) / 256, 256, 0, stream>>>(partial, nkc, potraw);
    finalize<<<1, NFEAT, 0, stream>>>(potraw, out);
}